// Round 22
// baseline (543.871 us; speedup 1.0000x reference)
//
#include <hip/hip_runtime.h>

// Channel attention (XCA windowed) for MI355X / gfx950.
// Shapes: b=2, C=384, H=W=224, heads=8, d=48, ps=7, nh=nw=32, windows=1024, s=49.
// Pipeline: [k_cvt] weights->bf16       [k_trx] x fp32 NCHW -> bf16 NHWC xt[b][p][c]
//           [k_gemm<0,9>] qkv 1x1 (MFMA, gld16, BK=64, swizzled, 2-phase dbuf)
//           [k_dw] depthwise 3x3, packed-pair conv (v_pk_fma_f32 target) + raw normsq
//           [k_attn] windowed channel attention, 2-barrier
//           [k_gemm<1,3>] proj 1x1 -> fp32 NCHW d_out
// Round-22: k_dw VALU cut — outputs computed as float2 pairs (packed-FMA
// eligible: 63 scalar FMA/phase -> ~36 packed ops) and s2 accumulated on raw
// outputs (drops 49 bf2f re-converts). VALUBusy 37% was k_dw's top pipe.
// ws aliasing: xt overlays qkv2 region (dead before k_dw); ao overlays qkv.

#define NB     2
#define CC     384
#define C3     1152
#define HH     224
#define WW2    224
#define HW     50176
#define NHEADS 8
#define DD     48
#define PSZ    7
#define NWINS  1024
#define SS     49
#define SSP    56                 // padded record: 112 B, 16-B aligned; slot 49 = 0, slots 50-51 = fp32 normsq
#define WSR    (NWINS*SSP)        // 57344: per-channel stride in qkv2

typedef unsigned int  u32;
typedef unsigned short u16;
typedef __bf16 bf16x8 __attribute__((ext_vector_type(8)));
typedef float  f32x4  __attribute__((ext_vector_type(4)));
typedef float  f32x2  __attribute__((ext_vector_type(2)));

// native HW convert (RNE)
__device__ __forceinline__ u16 f2bf(float f){
  union { __bf16 h; u16 u; } v; v.h = (__bf16)f; return v.u;
}
__device__ __forceinline__ float bf2f(u16 h){
  union { u32 u; float f; } v; v.u = ((u32)h) << 16;
  return v.f;
}
__device__ __forceinline__ float u16lo(u32 u){
  union { u32 u; float f; } v; v.u = u << 16; return v.f;
}
__device__ __forceinline__ float u16hi(u32 u){
  union { u32 u; float f; } v; v.u = u & 0xffff0000u; return v.f;
}

// async global->LDS, 16 B per lane
typedef __attribute__((address_space(3))) u32 as3_u32;
typedef __attribute__((address_space(1))) const u32 as1_u32;
__device__ __forceinline__ void gld16(const void* g, void* l){
  __builtin_amdgcn_global_load_lds((as1_u32*)(unsigned long long)(g),
                                   (as3_u32*)(u32)(unsigned long long)(l),
                                   16, 0, 0);
}

// T1 bijective XCD-chunk swizzle (nwg % 8 == 0 for all our grids).
__device__ __forceinline__ int xcdswz(int bid, int cpx){
  return (bid & 7)*cpx + (bid >> 3);
}

// XOR swizzle for LDS tiles with 64-ushort (128 B) rows (attn tiles).
__device__ __forceinline__ int swz(int row, int col){
  return row*64 + (col ^ ((row & 7) << 3));
}
__device__ __forceinline__ int swzc(int row, int c){    // chunk-granule form
  return row*64 + 8*(c ^ (row & 7));
}

// ---------------- weight conversion ----------------
__global__ void k_cvt(const float* __restrict__ qw, const float* __restrict__ pw,
                      u16* __restrict__ qwb, u16* __restrict__ pwb){
  int i = blockIdx.x * 256 + threadIdx.x;
  if (i < C3*CC) qwb[i] = f2bf(qw[i]);
  if (i < CC*CC) pwb[i] = f2bf(pw[i]);
}

// ---------------- sentinel (ws too small) ----------------
__global__ void k_sentinel(float* __restrict__ out, int n){
  int i = blockIdx.x * 256 + threadIdx.x;
  if (i < n) out[i] = 12345.0f;
}

// ---------------- x transpose+convert: NCHW fp32 -> NHWC bf16 ----------------
#define CPAD 386
__global__ __launch_bounds__(256) void k_trx(const float* __restrict__ x,
                                             u16* __restrict__ xt){
  const int pt = blockIdx.x, b = blockIdx.y, tid = threadIdx.x;
  __shared__ u16 t[64*CPAD];
  const float* xb = x + (size_t)b*CC*HW + pt*64;
  #pragma unroll
  for (int it=0; it<24; ++it){
    int i = tid + it*256;
    int c = i >> 4, p4 = (i & 15)*4;
    float4 v = *(const float4*)(xb + (size_t)c*HW + p4);
    t[(p4+0)*CPAD + c] = f2bf(v.x);
    t[(p4+1)*CPAD + c] = f2bf(v.y);
    t[(p4+2)*CPAD + c] = f2bf(v.z);
    t[(p4+3)*CPAD + c] = f2bf(v.w);
  }
  __syncthreads();
  u32* dst = (u32*)(xt + ((size_t)b*HW + (size_t)pt*64)*CC);
  #pragma unroll
  for (int it=0; it<48; ++it){
    int j = tid + it*256;
    int p = j / 192, c2 = j - p*192;
    dst[j] = *(const u32*)(t + p*CPAD + c2*2);
  }
}

// ---------------- 1x1-conv GEMM (BK=64, swizzled, 2-phase dbuf) ----------------
template<int OUT_F32, int MT, int CPX>
__global__ __launch_bounds__(256) void k_gemm(const u16* __restrict__ A,
    const u16* __restrict__ B, void* __restrict__ Cdst){
  __shared__ __align__(16) u16 As0[128*64], Bs0[128*64];   // 32 KB
  __shared__ __align__(16) u16 As1[128*64], Bs1[128*64];   // 32 KB
  const int wg = xcdswz(blockIdx.x, CPX);
  const int m0 = (wg % MT) * 128;
  const int t1 = wg / MT;
  const int n0 = (t1 % 392) * 128;
  const int b  = t1 / 392;
  const int M  = MT * 128;
  const int tid = threadIdx.x, lane = tid & 63, wv = tid >> 6;
  const int wm = (wv & 1) * 64, wn = (wv >> 1) * 64;
  const int lr = lane & 15, lg = lane >> 4;
  const u16* Bb = B + (size_t)b*HW*CC;

  f32x4 acc[4][4];
  #pragma unroll
  for (int i=0;i<4;++i)
    #pragma unroll
    for (int j=0;j<4;++j) acc[i][j] = {0.f,0.f,0.f,0.f};

  const int srow[4] = { (tid+  0)>>3, (tid+256)>>3, (tid+512)>>3, (tid+768)>>3 };
  const int sc8  = tid & 7;

  #define STAGE(AD, BD, K0) {                                             \
    _Pragma("unroll")                                                     \
    for (int i=0;i<4;++i){                                                \
      int row = srow[i];                                                  \
      int csrc = sc8 ^ (row & 7);                                         \
      gld16(A  + (size_t)(m0+row)*CC + (K0) + csrc*8, AD + (i*256+tid)*8);\
      gld16(Bb + (size_t)(n0+row)*CC + (K0) + csrc*8, BD + (i*256+tid)*8);\
    } }

  #define COMPUTE(AD, BD) {                                               \
    _Pragma("unroll")                                                     \
    for (int ks=0; ks<2; ++ks){                                           \
      const int cp = (((ks*4 + lg) ^ (lr & 7)) << 3);                     \
      bf16x8 af[4], bfr[4];                                               \
      _Pragma("unroll")                                                   \
      for (int i=0;i<4;++i) af[i]  = *(const bf16x8*)(AD + (wm + i*16 + lr)*64 + cp); \
      _Pragma("unroll")                                                   \
      for (int j=0;j<4;++j) bfr[j] = *(const bf16x8*)(BD + (wn + j*16 + lr)*64 + cp); \
      _Pragma("unroll")                                                   \
      for (int i=0;i<4;++i)                                               \
        _Pragma("unroll")                                                 \
        for (int j=0;j<4;++j)                                             \
          acc[i][j] = __builtin_amdgcn_mfma_f32_16x16x32_bf16(af[i], bfr[j], acc[i][j], 0, 0, 0); \
    } }

  STAGE(As0, Bs0, 0)
  __syncthreads();
  #pragma unroll
  for (int kk2=0; kk2<3; ++kk2){
    const int k0 = kk2*128;
    if (kk2*2+1 < 6) STAGE(As1, Bs1, k0+64)
    COMPUTE(As0, Bs0)
    __syncthreads();
    if (kk2*2+2 < 6) STAGE(As0, Bs0, k0+128)
    COMPUTE(As1, Bs1)
    __syncthreads();
  }
  #undef STAGE
  #undef COMPUTE

  #pragma unroll
  for (int i=0;i<4;++i){
    #pragma unroll
    for (int j=0;j<4;++j){
      const int row = m0 + wm + i*16 + lg*4;
      const int col = n0 + wn + j*16 + lr;
      if (OUT_F32){
        float* Cp = (float*)Cdst + (size_t)b*M*HW;
        #pragma unroll
        for (int r=0;r<4;++r) Cp[(size_t)(row+r)*HW + col] = acc[i][j][r];
      } else {
        u16* Cp = (u16*)Cdst + (size_t)b*M*HW;
        #pragma unroll
        for (int r=0;r<4;++r) Cp[(size_t)(row+r)*HW + col] = f2bf(acc[i][j][r]);
      }
    }
  }
}

// ---------------- depthwise 3x3 + normsq — packed-pair conv ----------------
// Block = (wy, 2ch, b) x 64 threads; thread = (ch, wx). Outputs per row-phase
// computed as 3 float2 pairs + 1 scalar -> v_pk_fma_f32 eligible; s2 on raw.
#define DWL 240    // lds row: 8 pad | 224 data | halo slot 232 | spare (u16)
__global__ __launch_bounds__(64) void k_dw(const u16* __restrict__ qkv,
    const float* __restrict__ dww, u16* __restrict__ qkv2){
  const int wg = xcdswz(blockIdx.x, 4608);
  const int wy = wg & 31;
  const int t1 = wg >> 5;
  const int o0 = (t1 % 576) * 2;
  const int b  = t1 / 576;
  const int tid = threadIdx.x;
  __shared__ __align__(16) u16 lin[2*9*DWL];   // 8640 B

  const int y0 = wy*PSZ - 1;

  if (tid < 36){
    int ch = tid/18, rem = tid%18, r = rem>>1;
    lin[ch*9*DWL + r*DWL + ((rem&1) ? 232 : 7)] = 0;
  }

  #pragma unroll
  for (int it=0; it<8; ++it){
    int i = tid + it*64;
    if (i < 504){
      int ch = i / 252, rem = i - ch*252;
      int r = rem / 28, c16 = rem - r*28;
      int y = y0 + r;
      uint4 v = {0,0,0,0};
      if (y >= 0 && y < HH)
        v = *(const uint4*)(qkv + (size_t)(b*C3 + o0 + ch)*HW + (size_t)y*WW2 + c16*8);
      *(uint4*)(lin + ch*9*DWL + r*DWL + 8 + c16*8) = v;
    }
  }
  __syncthreads();

  {
    const int ch = tid >> 5, wx = tid & 31;
    const u16* L = lin + ch*9*DWL;
    const int xb = wx*PSZ;
    const int s0 = (xb+7) & ~1;
    const bool par = (xb+7) & 1;

    float wk[9];
    #pragma unroll
    for (int i=0;i<9;++i) wk[i] = dww[(o0+ch)*9 + i];

    float tr[3][9];
    #define LOADROW(slot, r) {                                   \
      u32 u0 = *(const u32*)(L + (r)*DWL + s0);                  \
      u32 u1 = *(const u32*)(L + (r)*DWL + s0 + 2);              \
      u32 u2 = *(const u32*)(L + (r)*DWL + s0 + 4);              \
      u32 u3 = *(const u32*)(L + (r)*DWL + s0 + 6);              \
      u32 u4 = *(const u32*)(L + (r)*DWL + s0 + 8);              \
      float a0=u16lo(u0),a1=u16hi(u0),a2=u16lo(u1),a3=u16hi(u1); \
      float a4=u16lo(u2),a5=u16hi(u2),a6=u16lo(u3),a7=u16hi(u3); \
      float a8=u16lo(u4),a9=u16hi(u4);                           \
      tr[slot][0]=par?a1:a0; tr[slot][1]=par?a2:a1;              \
      tr[slot][2]=par?a3:a2; tr[slot][3]=par?a4:a3;              \
      tr[slot][4]=par?a5:a4; tr[slot][5]=par?a6:a5;              \
      tr[slot][6]=par?a7:a6; tr[slot][7]=par?a8:a7;              \
      tr[slot][8]=par?a9:a8; }

    LOADROW(0, 0)
    LOADROW(1, 1)

    u32 pk[28];
    pk[24] = 0; pk[25] = 0; pk[26] = 0; pk[27] = 0;
    float s2 = 0.f;
    #pragma unroll
    for (int pi=0; pi<7; ++pi){
      LOADROW((pi+2)%3, pi+2)
      const float* r0 = tr[pi%3];
      const float* r1 = tr[(pi+1)%3];
      const float* r2 = tr[(pi+2)%3];
      // packed pairs: (o0,o1) (o2,o3) (o4,o5) via float2 FMA (v_pk_fma_f32), o6 scalar
      f32x2 p01 = {0.f,0.f}, p23 = {0.f,0.f}, p45 = {0.f,0.f};
      float o6 = 0.f;
      #pragma unroll
      for (int kx=0;kx<3;++kx){
        const float w0 = wk[kx], w1 = wk[3+kx], w2 = wk[6+kx];
        f32x2 b01 = {r0[0+kx], r0[1+kx]};  p01 += w0*b01;
        f32x2 c01 = {r1[0+kx], r1[1+kx]};  p01 += w1*c01;
        f32x2 d01 = {r2[0+kx], r2[1+kx]};  p01 += w2*d01;
        f32x2 b23 = {r0[2+kx], r0[3+kx]};  p23 += w0*b23;
        f32x2 c23 = {r1[2+kx], r1[3+kx]};  p23 += w1*c23;
        f32x2 d23 = {r2[2+kx], r2[3+kx]};  p23 += w2*d23;
        f32x2 b45 = {r0[4+kx], r0[5+kx]};  p45 += w0*b45;
        f32x2 c45 = {r1[4+kx], r1[5+kx]};  p45 += w1*c45;
        f32x2 d45 = {r2[4+kx], r2[5+kx]};  p45 += w2*d45;
        o6 += w0*r0[6+kx] + w1*r1[6+kx] + w2*r2[6+kx];
      }
      float o[7] = {p01[0], p01[1], p23[0], p23[1], p45[0], p45[1], o6};
      #pragma unroll
      for (int pj=0; pj<7; ++pj){
        int idx = pi*7 + pj;
        s2 += o[pj]*o[pj];              // raw accumulate (saves 49 bf2f)
        u16 bv = f2bf(o[pj]);
        if ((idx & 1) == 0) pk[idx>>1] = (u32)bv;
        else                pk[idx>>1] |= ((u32)bv) << 16;
      }
    }
    pk[25] = __float_as_uint(s2);
    u16* rec = qkv2 + ((size_t)(b*C3 + o0 + ch)*NWINS + (size_t)(wy*32 + wx))*SSP;
    #pragma unroll
    for (int i=0;i<7;++i) *(uint4*)(rec + i*8) = *(const uint4*)(pk + i*4);
    #undef LOADROW
  }
}

// ---------------- windowed channel attention — 2-barrier version ----------------
__global__ __launch_bounds__(256) void k_attn(const u16* __restrict__ qkv2,
    const float* __restrict__ temp, u16* __restrict__ aout){
  const int h = blockIdx.x, win = blockIdx.y, b = blockIdx.z;
  const int tid = threadIdx.x, lane = tid & 63, wv = tid >> 6;
  const int lr = lane & 15, lg = lane >> 4;

  __shared__ __align__(16) u16 q_s[48*64], k_s[48*64], v_t[64*64], p_s[48*64];
  __shared__ float invq[48], invk[48];

  const u16* qsrc = qkv2 + ((size_t)(b*C3 +        h*DD)*NWINS + win)*SSP;
  const u16* ksrc = qkv2 + ((size_t)(b*C3 + CC   + h*DD)*NWINS + win)*SSP;
  const u16* vsrc = qkv2 + ((size_t)(b*C3 + 2*CC + h*DD)*NWINS + win)*SSP;

  #pragma unroll
  for (int j=0;j<4;++j){
    int g = j*256 + tid;
    if (g < 1008){
      int t  = g / 336;
      int gi = g - t*336;
      int dc = gi / 7, c = gi - dc*7;
      const u16* src = (t==0) ? qsrc : (t==1) ? ksrc : vsrc;
      uint4 v = *(const uint4*)(src + (size_t)dc*WSR + c*8);
      if (t < 2){
        if (c == 6){ v.y = 0u; v.z = 0u; v.w = 0u; }
        u16* dstt = (t==0) ? q_s : k_s;
        *(uint4*)(dstt + swzc(dc, c)) = v;
      } else {
        if (c < 6){
          int s0b = 8*c;
          u32 ws[4] = {v.x, v.y, v.z, v.w};
          #pragma unroll
          for (int q2=0; q2<4; ++q2){
            v_t[swz(s0b + 2*q2,     dc)] = (u16)(ws[q2] & 0xffffu);
            v_t[swz(s0b + 2*q2 + 1, dc)] = (u16)(ws[q2] >> 16);
          }
        } else {
          v_t[swz(48, dc)] = (u16)(v.x & 0xffffu);
        }
      }
    }
  }
  {
    const uint4 z = {0u,0u,0u,0u};
    #pragma unroll
    for (int j=0;j<2;++j){
      int g = j*256 + tid;
      if (g < 96){
        int t = g / 48, row = g - t*48;
        u16* dstt = (t==0) ? q_s : k_s;
        *(uint4*)(dstt + swzc(row, 7)) = z;
      } else if (g < 224){
        int i = g - 96, row = i >> 1, c = 6 + (i & 1);
        *(uint4*)(v_t + swzc(row, c)) = z;
      } else if (g < 314){
        int i = g - 224, row = 49 + i/6, c = i - (i/6)*6;
        *(uint4*)(v_t + swzc(row, c)) = z;
      } else if (g < 410){
        int i = g - 314, row = i >> 1, c = 6 + (i & 1);
        *(uint4*)(p_s + swzc(row, c)) = z;
      }
    }
  }
  if (tid < 96){
    const int rr = (tid < 48) ? tid : tid - 48;
    const u16* src = (tid < 48) ? qsrc : ksrc;
    float ns;
    { u32 u = *(const u32*)(src + (size_t)rr*WSR + 50); ns = __uint_as_float(u); }
    float inv = 1.f / fmaxf(sqrtf(ns), 1e-12f);
    if (tid < 48) invq[rr] = inv * temp[h]; else invk[rr] = inv;
  }
  __syncthreads();                                   // B1

  if (wv < 3){
    const int ti = wv;
    f32x4 c3[3];
    #pragma unroll
    for (int tj=0;tj<3;++tj) c3[tj] = {0.f,0.f,0.f,0.f};
    #pragma unroll
    for (int tj=0;tj<3;++tj){
      #pragma unroll
      for (int ks=0; ks<2; ++ks){
        bf16x8 a  = *(const bf16x8*)(q_s + swz(ti*16+lr, ks*32 + lg*8));
        bf16x8 bb = *(const bf16x8*)(k_s + swz(tj*16+lr, ks*32 + lg*8));
        c3[tj] = __builtin_amdgcn_mfma_f32_16x16x32_bf16(a, bb, c3[tj], 0,0,0);
      }
    }
    const float ik0 = invk[lr], ik1 = invk[16+lr], ik2 = invk[32+lr];
    #pragma unroll
    for (int r=0;r<4;++r){
      const int row = ti*16 + lg*4 + r;
      const float iq = invq[row];
      float l0 = c3[0][r]*iq*ik0, l1 = c3[1][r]*iq*ik1, l2 = c3[2][r]*iq*ik2;
      float m = fmaxf(fmaxf(l0,l1),l2);
      m = fmaxf(m, __shfl_xor(m,1)); m = fmaxf(m, __shfl_xor(m,2));
      m = fmaxf(m, __shfl_xor(m,4)); m = fmaxf(m, __shfl_xor(m,8));
      float e0 = __expf(l0-m), e1 = __expf(l1-m), e2 = __expf(l2-m);
      float s = e0+e1+e2;
      s += __shfl_xor(s,1); s += __shfl_xor(s,2);
      s += __shfl_xor(s,4); s += __shfl_xor(s,8);
      const float is = 1.f / s;
      p_s[swz(row, lr)]    = f2bf(e0*is);
      p_s[swz(row, 16+lr)] = f2bf(e1*is);
      p_s[swz(row, 32+lr)] = f2bf(e2*is);
    }
  }
  __syncthreads();                                   // B2

  const int wy = win >> 5, wx = win & 31;
  u16* ab = aout + (size_t)b*HW*CC + (size_t)h*DD;
  for (int t = wv; t < 12; t += 4){
    int ti = t >> 2, tj = t & 3;
    f32x4 c = {0.f,0.f,0.f,0.f};
    #pragma unroll
    for (int ks=0; ks<2; ++ks){
      bf16x8 a  = *(const bf16x8*)(p_s + swz(ti*16+lr, ks*32 + lg*8));
      bf16x8 bb = *(const bf16x8*)(v_t + swz(tj*16+lr, ks*32 + lg*8));
      c = __builtin_amdgcn_mfma_f32_16x16x32_bf16(a, bb, c, 0,0,0);
    }
    int scol = tj*16 + lr;
    if (scol < SS){
      int pi = scol / PSZ, pj = scol - pi*PSZ;
      size_t p = (size_t)(wy*PSZ + pi)*WW2 + wx*PSZ + pj;
      u32 lo = (u32)f2bf(c[0]) | ((u32)f2bf(c[1]) << 16);
      u32 hi = (u32)f2bf(c[2]) | ((u32)f2bf(c[3]) << 16);
      u32* dst = (u32*)(ab + p*CC + ti*16 + lg*4);
      dst[0] = lo; dst[1] = hi;
    }
  }
}

// ---------------- launch ----------------
extern "C" void kernel_launch(void* const* d_in, const int* in_sizes, int n_in,
                              void* d_out, int out_size, void* d_ws, size_t ws_size,
                              hipStream_t stream) {
  const float* x     = (const float*)d_in[0];
  const float* qkvw  = (const float*)d_in[1];
  const float* dww   = (const float*)d_in[2];
  const float* temp  = (const float*)d_in[3];
  const float* projw = (const float*)d_in[4];
  float* out = (float*)d_out;

  const size_t SZ_QKV   = (size_t)NB*C3*HW*2;            // 231,211,008
  const size_t SZ_QKV2  = (size_t)NB*C3*NWINS*SSP*2;     // 264,241,152
  const size_t OFF_QKV2 = SZ_QKV;
  const size_t OFF_W1   = OFF_QKV2 + SZ_QKV2;            // 495,452,160
  const size_t OFF_W2   = OFF_W1 + (size_t)C3*CC*2;
  const size_t NEEDED   = OFF_W2 + (size_t)CC*CC*2;      // 496,631,808

  if (ws_size < NEEDED){
    k_sentinel<<<(out_size + 255)/256, 256, 0, stream>>>(out, out_size);
    return;
  }
  char* ws = (char*)d_ws;
  u16* qkv  = (u16*)ws;
  u16* qkv2 = (u16*)(ws + OFF_QKV2);
  u16* xt   = (u16*)(ws + OFF_QKV2);    // aliases qkv2 (xt dead before k_dw)
  u16* ao   = (u16*)ws;                 // aliases qkv
  u16* qwb  = (u16*)(ws + OFF_W1);
  u16* pwb  = (u16*)(ws + OFF_W2);

  k_cvt<<<dim3((C3*CC)/256), 256, 0, stream>>>(qkvw, projw, qwb, pwb);
  k_trx<<<dim3(784, NB), 256, 0, stream>>>(x, xt);
  k_gemm<0,9,882><<<dim3(7056), 256, 0, stream>>>(qwb, xt, qkv);   // 9*392*2, cpx=882
  k_dw<<<dim3(36864), 64, 0, stream>>>(qkv, dww, qkv2);            // 32*576*2, cpx=4608
  k_attn<<<dim3(NHEADS, NWINS, NB), 256, 0, stream>>>(qkv2, temp, ao);
  k_gemm<1,3,294><<<dim3(2352), 256, 0, stream>>>(pwb, ao, out);   // 3*392*2, cpx=294
}

// Round 23
// 537.136 us; speedup vs baseline: 1.0125x; 1.0125x over previous
//
#include <hip/hip_runtime.h>

// Channel attention (XCA windowed) for MI355X / gfx950.
// Shapes: b=2, C=384, H=W=224, heads=8, d=48, ps=7, nh=nw=32, windows=1024, s=49.
// Pipeline: [k_cvt] weights->bf16       [k_trx] x fp32 NCHW -> bf16 NHWC xt[b][p][c]
//           [k_gemm<0,9>] qkv 1x1 (MFMA, gld16, BK=64, swizzled, 2-phase dbuf)
//           [k_dw] depthwise 3x3, 64-thread single-wave blocks (plateau: 152us x6 variants)
//           [k_attn] windowed channel attention, 2-barrier (pad-zeroing fused into staging)
//           [k_gemm<1,3>] proj 1x1 -> fp32 NCHW d_out
// Round-23: revert to R21 (best measured, 540.4us). R22's packed-pair conv
// regressed (+16 VGPR, dur +4us despite -3% VALUBusy) — k_dw is latency-bound,
// not issue-bound; 6th falsified lever. trx/proj at HBM BW; qkv gemm at 592 TF
// (2-phase/BK64/swizzle/T1 counter-verified); dw/attn at residency plateaus.
// ws aliasing: xt overlays qkv2 region (dead before k_dw); ao overlays qkv.

#define NB     2
#define CC     384
#define C3     1152
#define HH     224
#define WW2    224
#define HW     50176
#define NHEADS 8
#define DD     48
#define PSZ    7
#define NWINS  1024
#define SS     49
#define SSP    56                 // padded record: 112 B, 16-B aligned; slot 49 = 0, slots 50-51 = fp32 normsq
#define WSR    (NWINS*SSP)        // 57344: per-channel stride in qkv2

typedef unsigned int  u32;
typedef unsigned short u16;
typedef __bf16 bf16x8 __attribute__((ext_vector_type(8)));
typedef float  f32x4  __attribute__((ext_vector_type(4)));

// native HW convert (RNE)
__device__ __forceinline__ u16 f2bf(float f){
  union { __bf16 h; u16 u; } v; v.h = (__bf16)f; return v.u;
}
__device__ __forceinline__ float bf2f(u16 h){
  union { u32 u; float f; } v; v.u = ((u32)h) << 16;
  return v.f;
}
__device__ __forceinline__ float u16lo(u32 u){
  union { u32 u; float f; } v; v.u = u << 16; return v.f;
}
__device__ __forceinline__ float u16hi(u32 u){
  union { u32 u; float f; } v; v.u = u & 0xffff0000u; return v.f;
}

// async global->LDS, 16 B per lane
typedef __attribute__((address_space(3))) u32 as3_u32;
typedef __attribute__((address_space(1))) const u32 as1_u32;
__device__ __forceinline__ void gld16(const void* g, void* l){
  __builtin_amdgcn_global_load_lds((as1_u32*)(unsigned long long)(g),
                                   (as3_u32*)(u32)(unsigned long long)(l),
                                   16, 0, 0);
}

// T1 bijective XCD-chunk swizzle (nwg % 8 == 0 for all our grids).
__device__ __forceinline__ int xcdswz(int bid, int cpx){
  return (bid & 7)*cpx + (bid >> 3);
}

// XOR swizzle for LDS tiles with 64-ushort (128 B) rows (attn tiles).
// Operates on 8-u16 granules: 16-B chunk c of row r lands at r*64+8*(c^(r&7)).
__device__ __forceinline__ int swz(int row, int col){
  return row*64 + (col ^ ((row & 7) << 3));
}
__device__ __forceinline__ int swzc(int row, int c){    // chunk-granule form
  return row*64 + 8*(c ^ (row & 7));
}

// ---------------- weight conversion ----------------
__global__ void k_cvt(const float* __restrict__ qw, const float* __restrict__ pw,
                      u16* __restrict__ qwb, u16* __restrict__ pwb){
  int i = blockIdx.x * 256 + threadIdx.x;
  if (i < C3*CC) qwb[i] = f2bf(qw[i]);
  if (i < CC*CC) pwb[i] = f2bf(pw[i]);
}

// ---------------- sentinel (ws too small) ----------------
__global__ void k_sentinel(float* __restrict__ out, int n){
  int i = blockIdx.x * 256 + threadIdx.x;
  if (i < n) out[i] = 12345.0f;
}

// ---------------- x transpose+convert: NCHW fp32 -> NHWC bf16 ----------------
#define CPAD 386
__global__ __launch_bounds__(256) void k_trx(const float* __restrict__ x,
                                             u16* __restrict__ xt){
  const int pt = blockIdx.x, b = blockIdx.y, tid = threadIdx.x;
  __shared__ u16 t[64*CPAD];
  const float* xb = x + (size_t)b*CC*HW + pt*64;
  #pragma unroll
  for (int it=0; it<24; ++it){
    int i = tid + it*256;
    int c = i >> 4, p4 = (i & 15)*4;
    float4 v = *(const float4*)(xb + (size_t)c*HW + p4);
    t[(p4+0)*CPAD + c] = f2bf(v.x);
    t[(p4+1)*CPAD + c] = f2bf(v.y);
    t[(p4+2)*CPAD + c] = f2bf(v.z);
    t[(p4+3)*CPAD + c] = f2bf(v.w);
  }
  __syncthreads();
  u32* dst = (u32*)(xt + ((size_t)b*HW + (size_t)pt*64)*CC);
  #pragma unroll
  for (int it=0; it<48; ++it){
    int j = tid + it*256;
    int p = j / 192, c2 = j - p*192;
    dst[j] = *(const u32*)(t + p*CPAD + c2*2);
  }
}

// ---------------- 1x1-conv GEMM (BK=64, swizzled, 2-phase dbuf) ----------------
template<int OUT_F32, int MT, int CPX>
__global__ __launch_bounds__(256) void k_gemm(const u16* __restrict__ A,
    const u16* __restrict__ B, void* __restrict__ Cdst){
  __shared__ __align__(16) u16 As0[128*64], Bs0[128*64];   // 32 KB
  __shared__ __align__(16) u16 As1[128*64], Bs1[128*64];   // 32 KB
  const int wg = xcdswz(blockIdx.x, CPX);
  const int m0 = (wg % MT) * 128;
  const int t1 = wg / MT;
  const int n0 = (t1 % 392) * 128;
  const int b  = t1 / 392;
  const int M  = MT * 128;
  const int tid = threadIdx.x, lane = tid & 63, wv = tid >> 6;
  const int wm = (wv & 1) * 64, wn = (wv >> 1) * 64;
  const int lr = lane & 15, lg = lane >> 4;
  const u16* Bb = B + (size_t)b*HW*CC;

  f32x4 acc[4][4];
  #pragma unroll
  for (int i=0;i<4;++i)
    #pragma unroll
    for (int j=0;j<4;++j) acc[i][j] = {0.f,0.f,0.f,0.f};

  const int srow[4] = { (tid+  0)>>3, (tid+256)>>3, (tid+512)>>3, (tid+768)>>3 };
  const int sc8  = tid & 7;

  #define STAGE(AD, BD, K0) {                                             \
    _Pragma("unroll")                                                     \
    for (int i=0;i<4;++i){                                                \
      int row = srow[i];                                                  \
      int csrc = sc8 ^ (row & 7);                                         \
      gld16(A  + (size_t)(m0+row)*CC + (K0) + csrc*8, AD + (i*256+tid)*8);\
      gld16(Bb + (size_t)(n0+row)*CC + (K0) + csrc*8, BD + (i*256+tid)*8);\
    } }

  #define COMPUTE(AD, BD) {                                               \
    _Pragma("unroll")                                                     \
    for (int ks=0; ks<2; ++ks){                                           \
      const int cp = (((ks*4 + lg) ^ (lr & 7)) << 3);                     \
      bf16x8 af[4], bfr[4];                                               \
      _Pragma("unroll")                                                   \
      for (int i=0;i<4;++i) af[i]  = *(const bf16x8*)(AD + (wm + i*16 + lr)*64 + cp); \
      _Pragma("unroll")                                                   \
      for (int j=0;j<4;++j) bfr[j] = *(const bf16x8*)(BD + (wn + j*16 + lr)*64 + cp); \
      _Pragma("unroll")                                                   \
      for (int i=0;i<4;++i)                                               \
        _Pragma("unroll")                                                 \
        for (int j=0;j<4;++j)                                             \
          acc[i][j] = __builtin_amdgcn_mfma_f32_16x16x32_bf16(af[i], bfr[j], acc[i][j], 0, 0, 0); \
    } }

  STAGE(As0, Bs0, 0)
  __syncthreads();
  #pragma unroll
  for (int kk2=0; kk2<3; ++kk2){
    const int k0 = kk2*128;
    if (kk2*2+1 < 6) STAGE(As1, Bs1, k0+64)
    COMPUTE(As0, Bs0)
    __syncthreads();
    if (kk2*2+2 < 6) STAGE(As0, Bs0, k0+128)
    COMPUTE(As1, Bs1)
    __syncthreads();
  }
  #undef STAGE
  #undef COMPUTE

  #pragma unroll
  for (int i=0;i<4;++i){
    #pragma unroll
    for (int j=0;j<4;++j){
      const int row = m0 + wm + i*16 + lg*4;
      const int col = n0 + wn + j*16 + lr;
      if (OUT_F32){
        float* Cp = (float*)Cdst + (size_t)b*M*HW;
        #pragma unroll
        for (int r=0;r<4;++r) Cp[(size_t)(row+r)*HW + col] = acc[i][j][r];
      } else {
        u16* Cp = (u16*)Cdst + (size_t)b*M*HW;
        #pragma unroll
        for (int r=0;r<4;++r) Cp[(size_t)(row+r)*HW + col] = f2bf(acc[i][j][r]);
      }
    }
  }
}

// ---------------- depthwise 3x3 + normsq — 64-thread single-wave blocks ----------------
#define DWL 240    // lds row: 8 pad | 224 data | halo slot 232 | spare (u16)
__global__ __launch_bounds__(64) void k_dw(const u16* __restrict__ qkv,
    const float* __restrict__ dww, u16* __restrict__ qkv2){
  const int wg = xcdswz(blockIdx.x, 4608);
  const int wy = wg & 31;
  const int t1 = wg >> 5;
  const int o0 = (t1 % 576) * 2;
  const int b  = t1 / 576;
  const int tid = threadIdx.x;
  __shared__ __align__(16) u16 lin[2*9*DWL];   // 8640 B

  const int y0 = wy*PSZ - 1;

  if (tid < 36){
    int ch = tid/18, rem = tid%18, r = rem>>1;
    lin[ch*9*DWL + r*DWL + ((rem&1) ? 232 : 7)] = 0;
  }

  #pragma unroll
  for (int it=0; it<8; ++it){
    int i = tid + it*64;
    if (i < 504){
      int ch = i / 252, rem = i - ch*252;
      int r = rem / 28, c16 = rem - r*28;
      int y = y0 + r;
      uint4 v = {0,0,0,0};
      if (y >= 0 && y < HH)
        v = *(const uint4*)(qkv + (size_t)(b*C3 + o0 + ch)*HW + (size_t)y*WW2 + c16*8);
      *(uint4*)(lin + ch*9*DWL + r*DWL + 8 + c16*8) = v;
    }
  }
  __syncthreads();

  {
    const int ch = tid >> 5, wx = tid & 31;
    const u16* L = lin + ch*9*DWL;
    const int xb = wx*PSZ;
    const int s0 = (xb+7) & ~1;
    const bool par = (xb+7) & 1;

    float wk[9];
    #pragma unroll
    for (int i=0;i<9;++i) wk[i] = dww[(o0+ch)*9 + i];

    float tr[3][9];
    #define LOADROW(slot, r) {                                   \
      u32 u0 = *(const u32*)(L + (r)*DWL + s0);                  \
      u32 u1 = *(const u32*)(L + (r)*DWL + s0 + 2);              \
      u32 u2 = *(const u32*)(L + (r)*DWL + s0 + 4);              \
      u32 u3 = *(const u32*)(L + (r)*DWL + s0 + 6);              \
      u32 u4 = *(const u32*)(L + (r)*DWL + s0 + 8);              \
      float a0=u16lo(u0),a1=u16hi(u0),a2=u16lo(u1),a3=u16hi(u1); \
      float a4=u16lo(u2),a5=u16hi(u2),a6=u16lo(u3),a7=u16hi(u3); \
      float a8=u16lo(u4),a9=u16hi(u4);                           \
      tr[slot][0]=par?a1:a0; tr[slot][1]=par?a2:a1;              \
      tr[slot][2]=par?a3:a2; tr[slot][3]=par?a4:a3;              \
      tr[slot][4]=par?a5:a4; tr[slot][5]=par?a6:a5;              \
      tr[slot][6]=par?a7:a6; tr[slot][7]=par?a8:a7;              \
      tr[slot][8]=par?a9:a8; }

    LOADROW(0, 0)
    LOADROW(1, 1)

    u32 pk[28];
    pk[24] = 0; pk[25] = 0; pk[26] = 0; pk[27] = 0;
    float s2 = 0.f;
    #pragma unroll
    for (int pi=0; pi<7; ++pi){
      LOADROW((pi+2)%3, pi+2)
      const float* r0 = tr[pi%3];
      const float* r1 = tr[(pi+1)%3];
      const float* r2 = tr[(pi+2)%3];
      float o[7];
      #pragma unroll
      for (int pj=0; pj<7; ++pj){
        float s = 0.f;
        #pragma unroll
        for (int kx=0;kx<3;++kx){
          s += wk[kx]  *r0[pj+kx];
          s += wk[3+kx]*r1[pj+kx];
          s += wk[6+kx]*r2[pj+kx];
        }
        o[pj] = s;
      }
      #pragma unroll
      for (int pj=0; pj<7; ++pj){
        int idx = pi*7 + pj;
        u16 bv = f2bf(o[pj]);
        float rv = bf2f(bv);
        s2 += rv*rv;
        if ((idx & 1) == 0) pk[idx>>1] = (u32)bv;
        else                pk[idx>>1] |= ((u32)bv) << 16;
      }
    }
    pk[25] = __float_as_uint(s2);
    u16* rec = qkv2 + ((size_t)(b*C3 + o0 + ch)*NWINS + (size_t)(wy*32 + wx))*SSP;
    #pragma unroll
    for (int i=0;i<7;++i) *(uint4*)(rec + i*8) = *(const uint4*)(pk + i*4);
    #undef LOADROW
  }
}

// ---------------- windowed channel attention — 2-barrier version ----------------
// Stage phase writes ALL live LDS plus targeted pad zeros (410 ds_write_b128):
//   q_s/k_s: staged chunks 0-6 (chunk6 masked; slot49=0 from k_dw) + zero chunk 7
//   v_t: transposed scatter covers [s:0..48][d:0..47]; zero chunks 6,7 all rows
//        and chunks 0-5 of rows 49-63
//   p_s: softmax writes cols 0-47; zero chunks 6,7 all 48 rows
// Barriers: B1 after stage+zeros+norms, B2 after softmax.
__global__ __launch_bounds__(256) void k_attn(const u16* __restrict__ qkv2,
    const float* __restrict__ temp, u16* __restrict__ aout){
  const int h = blockIdx.x, win = blockIdx.y, b = blockIdx.z;
  const int tid = threadIdx.x, lane = tid & 63, wv = tid >> 6;
  const int lr = lane & 15, lg = lane >> 4;

  __shared__ __align__(16) u16 q_s[48*64], k_s[48*64], v_t[64*64], p_s[48*64];
  __shared__ float invq[48], invk[48];

  const u16* qsrc = qkv2 + ((size_t)(b*C3 +        h*DD)*NWINS + win)*SSP;
  const u16* ksrc = qkv2 + ((size_t)(b*C3 + CC   + h*DD)*NWINS + win)*SSP;
  const u16* vsrc = qkv2 + ((size_t)(b*C3 + 2*CC + h*DD)*NWINS + win)*SSP;

  // ---- stage (1008 uint4 chunks) ----
  #pragma unroll
  for (int j=0;j<4;++j){
    int g = j*256 + tid;
    if (g < 1008){
      int t  = g / 336;                      // 0=q, 1=k, 2=v
      int gi = g - t*336;
      int dc = gi / 7, c = gi - dc*7;        // record, 16-B chunk
      const u16* src = (t==0) ? qsrc : (t==1) ? ksrc : vsrc;
      uint4 v = *(const uint4*)(src + (size_t)dc*WSR + c*8);
      if (t < 2){
        if (c == 6){ v.y = 0u; v.z = 0u; v.w = 0u; }   // slots 50-55 -> 0
        u16* dstt = (t==0) ? q_s : k_s;
        *(uint4*)(dstt + swzc(dc, c)) = v;
      } else {
        if (c < 6){
          int s0b = 8*c;
          u32 ws[4] = {v.x, v.y, v.z, v.w};
          #pragma unroll
          for (int q2=0; q2<4; ++q2){
            v_t[swz(s0b + 2*q2,     dc)] = (u16)(ws[q2] & 0xffffu);
            v_t[swz(s0b + 2*q2 + 1, dc)] = (u16)(ws[q2] >> 16);
          }
        } else {
          v_t[swz(48, dc)] = (u16)(v.x & 0xffffu);     // s=48 only
        }
      }
    }
  }
  // ---- targeted pad zeros (410 b128) ----
  {
    const uint4 z = {0u,0u,0u,0u};
    #pragma unroll
    for (int j=0;j<2;++j){
      int g = j*256 + tid;
      if (g < 96){                    // q_s/k_s chunk 7
        int t = g / 48, row = g - t*48;
        u16* dstt = (t==0) ? q_s : k_s;
        *(uint4*)(dstt + swzc(row, 7)) = z;
      } else if (g < 224){            // v_t chunks 6,7 all 64 rows
        int i = g - 96, row = i >> 1, c = 6 + (i & 1);
        *(uint4*)(v_t + swzc(row, c)) = z;
      } else if (g < 314){            // v_t rows 49-63, chunks 0-5
        int i = g - 224, row = 49 + i/6, c = i - (i/6)*6;
        *(uint4*)(v_t + swzc(row, c)) = z;
      } else if (g < 410){            // p_s chunks 6,7 all 48 rows
        int i = g - 314, row = i >> 1, c = 6 + (i & 1);
        *(uint4*)(p_s + swzc(row, c)) = z;
      }
    }
  }
  // ---- norm factors from record pad slots (fp32 at u16 offset 50) ----
  if (tid < 96){
    const int rr = (tid < 48) ? tid : tid - 48;
    const u16* src = (tid < 48) ? qsrc : ksrc;
    float ns;
    { u32 u = *(const u32*)(src + (size_t)rr*WSR + 50); ns = __uint_as_float(u); }
    float inv = 1.f / fmaxf(sqrtf(ns), 1e-12f);
    if (tid < 48) invq[rr] = inv * temp[h]; else invk[rr] = inv;
  }
  __syncthreads();                                   // B1

  if (wv < 3){
    const int ti = wv;
    f32x4 c3[3];
    #pragma unroll
    for (int tj=0;tj<3;++tj) c3[tj] = {0.f,0.f,0.f,0.f};
    #pragma unroll
    for (int tj=0;tj<3;++tj){
      #pragma unroll
      for (int ks=0; ks<2; ++ks){
        bf16x8 a  = *(const bf16x8*)(q_s + swz(ti*16+lr, ks*32 + lg*8));
        bf16x8 bb = *(const bf16x8*)(k_s + swz(tj*16+lr, ks*32 + lg*8));
        c3[tj] = __builtin_amdgcn_mfma_f32_16x16x32_bf16(a, bb, c3[tj], 0,0,0);
      }
    }
    const float ik0 = invk[lr], ik1 = invk[16+lr], ik2 = invk[32+lr];
    #pragma unroll
    for (int r=0;r<4;++r){
      const int row = ti*16 + lg*4 + r;
      const float iq = invq[row];
      float l0 = c3[0][r]*iq*ik0, l1 = c3[1][r]*iq*ik1, l2 = c3[2][r]*iq*ik2;
      float m = fmaxf(fmaxf(l0,l1),l2);
      m = fmaxf(m, __shfl_xor(m,1)); m = fmaxf(m, __shfl_xor(m,2));
      m = fmaxf(m, __shfl_xor(m,4)); m = fmaxf(m, __shfl_xor(m,8));
      float e0 = __expf(l0-m), e1 = __expf(l1-m), e2 = __expf(l2-m);
      float s = e0+e1+e2;
      s += __shfl_xor(s,1); s += __shfl_xor(s,2);
      s += __shfl_xor(s,4); s += __shfl_xor(s,8);
      const float is = 1.f / s;
      p_s[swz(row, lr)]    = f2bf(e0*is);
      p_s[swz(row, 16+lr)] = f2bf(e1*is);
      p_s[swz(row, 32+lr)] = f2bf(e2*is);
    }
  }
  __syncthreads();                                   // B2

  const int wy = win >> 5, wx = win & 31;
  u16* ab = aout + (size_t)b*HW*CC + (size_t)h*DD;
  for (int t = wv; t < 12; t += 4){
    int ti = t >> 2, tj = t & 3;
    f32x4 c = {0.f,0.f,0.f,0.f};
    #pragma unroll
    for (int ks=0; ks<2; ++ks){
      bf16x8 a  = *(const bf16x8*)(p_s + swz(ti*16+lr, ks*32 + lg*8));
      bf16x8 bb = *(const bf16x8*)(v_t + swz(tj*16+lr, ks*32 + lg*8));
      c = __builtin_amdgcn_mfma_f32_16x16x32_bf16(a, bb, c, 0,0,0);
    }
    int scol = tj*16 + lr;
    if (scol < SS){
      int pi = scol / PSZ, pj = scol - pi*PSZ;
      size_t p = (size_t)(wy*PSZ + pi)*WW2 + wx*PSZ + pj;
      u32 lo = (u32)f2bf(c[0]) | ((u32)f2bf(c[1]) << 16);
      u32 hi = (u32)f2bf(c[2]) | ((u32)f2bf(c[3]) << 16);
      u32* dst = (u32*)(ab + p*CC + ti*16 + lg*4);
      dst[0] = lo; dst[1] = hi;
    }
  }
}

// ---------------- launch ----------------
extern "C" void kernel_launch(void* const* d_in, const int* in_sizes, int n_in,
                              void* d_out, int out_size, void* d_ws, size_t ws_size,
                              hipStream_t stream) {
  const float* x     = (const float*)d_in[0];
  const float* qkvw  = (const float*)d_in[1];
  const float* dww   = (const float*)d_in[2];
  const float* temp  = (const float*)d_in[3];
  const float* projw = (const float*)d_in[4];
  float* out = (float*)d_out;

  const size_t SZ_QKV   = (size_t)NB*C3*HW*2;            // 231,211,008
  const size_t SZ_QKV2  = (size_t)NB*C3*NWINS*SSP*2;     // 264,241,152
  const size_t OFF_QKV2 = SZ_QKV;
  const size_t OFF_W1   = OFF_QKV2 + SZ_QKV2;            // 495,452,160
  const size_t OFF_W2   = OFF_W1 + (size_t)C3*CC*2;
  const size_t NEEDED   = OFF_W2 + (size_t)CC*CC*2;      // 496,631,808

  if (ws_size < NEEDED){
    k_sentinel<<<(out_size + 255)/256, 256, 0, stream>>>(out, out_size);
    return;
  }
  char* ws = (char*)d_ws;
  u16* qkv  = (u16*)ws;
  u16* qkv2 = (u16*)(ws + OFF_QKV2);
  u16* xt   = (u16*)(ws + OFF_QKV2);    // aliases qkv2 (xt dead before k_dw)
  u16* ao   = (u16*)ws;                 // aliases qkv
  u16* qwb  = (u16*)(ws + OFF_W1);
  u16* pwb  = (u16*)(ws + OFF_W2);

  k_cvt<<<dim3((C3*CC)/256), 256, 0, stream>>>(qkvw, projw, qwb, pwb);
  k_trx<<<dim3(784, NB), 256, 0, stream>>>(x, xt);
  k_gemm<0,9,882><<<dim3(7056), 256, 0, stream>>>(qwb, xt, qkv);   // 9*392*2, cpx=882
  k_dw<<<dim3(36864), 64, 0, stream>>>(qkv, dww, qkv2);            // 32*576*2, cpx=4608
  k_attn<<<dim3(NHEADS, NWINS, NB), 256, 0, stream>>>(qkv2, temp, ao);
  k_gemm<1,3,294><<<dim3(2352), 256, 0, stream>>>(pwb, ao, out);   // 3*392*2, cpx=294
}